// Round 2
// baseline (1367.906 us; speedup 1.0000x reference)
//
#include <hip/hip_runtime.h>
#include <math.h>

#define B 8
#define C 512
#define K 19
#define HW 16384
#define L2E 1.44269504088896340736f

#define NW 4                     // waves per block
#define CPW 4                    // c-rows per wave
#define CPB (CPW * NW)           // 16 c-rows per block
#define CG (C / CPB)             // 32 c-groups
#define NSC 4                    // s-chunks
#define SCHUNK (HW / NSC)        // 4096 s per block
#define TS 256                   // s-tile staged in LDS
#define NT (SCHUNK / TS)         // 16 tiles per block

// Kernel 1: per-(b,k) softmax stats. stats[row*2] = -max*log2e, stats[row*2+1] = 1/Z
__global__ __launch_bounds__(1024)
void softmax_stats_kernel(const float* __restrict__ aux, float* __restrict__ stats) {
    int row = blockIdx.x;                          // 0 .. B*K-1
    const float4* x4 = (const float4*)(aux + (size_t)row * HW);
    int tid  = threadIdx.x;
    int lane = tid & 63;
    int wave = tid >> 6;
    __shared__ float red[16];

    // pass 1: max  (HW/4 = 4096 float4s, 1024 threads -> 4 iters)
    float m = -INFINITY;
    #pragma unroll
    for (int i = 0; i < 4; i++) {
        float4 v = x4[tid + i * 1024];
        m = fmaxf(m, fmaxf(fmaxf(v.x, v.y), fmaxf(v.z, v.w)));
    }
    #pragma unroll
    for (int off = 32; off > 0; off >>= 1) m = fmaxf(m, __shfl_xor(m, off, 64));
    if (lane == 0) red[wave] = m;
    __syncthreads();
    #pragma unroll
    for (int w = 0; w < 16; w++) m = fmaxf(m, red[w]);
    __syncthreads();   // red reused below

    // pass 2: sum of exp
    float ssum = 0.f;
    #pragma unroll
    for (int i = 0; i < 4; i++) {
        float4 v = x4[tid + i * 1024];
        ssum += exp2f((v.x - m) * L2E);
        ssum += exp2f((v.y - m) * L2E);
        ssum += exp2f((v.z - m) * L2E);
        ssum += exp2f((v.w - m) * L2E);
    }
    #pragma unroll
    for (int off = 32; off > 0; off >>= 1) ssum += __shfl_xor(ssum, off, 64);
    if (lane == 0) red[wave] = ssum;
    __syncthreads();
    if (tid == 0) {
        float Z = 0.f;
        #pragma unroll
        for (int w = 0; w < 16; w++) Z += red[w];
        stats[row * 2]     = -m * L2E;
        stats[row * 2 + 1] = 1.0f / Z;
    }
}

// Kernel 2: per-tile, probs computed ONCE per block into LDS, then each wave
// FMAs its 4 c-rows against the staged probs. acc[4][19]=76 VGPRs -> no spill.
__global__ __launch_bounds__(256, 4)
void gather_kernel(const float* __restrict__ feats, const float* __restrict__ aux,
                   const float* __restrict__ stats, float* __restrict__ out) {
    __shared__ float plds[K][TS];

    int bid  = blockIdx.x;                 // 0 .. B*CG*NSC-1 (=1024)
    int sc   = bid & (NSC - 1);
    int cg   = (bid / NSC) & (CG - 1);
    int b    = bid / (NSC * CG);
    int tid  = threadIdx.x;
    int lane = tid & 63;
    int wave = tid >> 6;
    int c0   = cg * CPB + wave * CPW;

    const float* Abase = aux   + (size_t)b * K * HW + sc * SCHUNK;
    const float* Fbase = feats + ((size_t)b * C + c0) * HW + sc * SCHUNK;
    const float* S     = stats + (size_t)b * K * 2;

    // force softmax stats into SGPRs (38 VGPRs would threaten the budget)
    float negml[K], invz[K];
    #pragma unroll
    for (int k = 0; k < K; k++) {
        negml[k] = __int_as_float(__builtin_amdgcn_readfirstlane(__float_as_int(S[2 * k])));
        invz[k]  = __int_as_float(__builtin_amdgcn_readfirstlane(__float_as_int(S[2 * k + 1])));
    }

    float acc[CPW][K];
    #pragma unroll
    for (int c = 0; c < CPW; c++)
        #pragma unroll
        for (int k = 0; k < K; k++) acc[c][k] = 0.f;

    for (int t = 0; t < NT; t++) {
        int s0 = t * TS;

        // phase A: all 256 threads stage probs for this tile (once per block)
        __syncthreads();    // previous tile's readers done before overwrite
        #pragma unroll
        for (int k = 0; k < K; k++) {
            float a = Abase[k * HW + s0 + tid];
            plds[k][tid] = exp2f(fmaf(a, L2E, negml[k])) * invz[k];
        }
        __syncthreads();

        // phase B: float4 feats + ds_read_b128 probs
        float4 f[CPW];
        #pragma unroll
        for (int c = 0; c < CPW; c++)
            f[c] = *(const float4*)(Fbase + c * HW + s0 + lane * 4);
        #pragma unroll
        for (int k = 0; k < K; k++) {
            float4 p4 = *(const float4*)(&plds[k][lane * 4]);
            #pragma unroll
            for (int c = 0; c < CPW; c++) {
                acc[c][k] = fmaf(p4.x, f[c].x, acc[c][k]);
                acc[c][k] = fmaf(p4.y, f[c].y, acc[c][k]);
                acc[c][k] = fmaf(p4.z, f[c].z, acc[c][k]);
                acc[c][k] = fmaf(p4.w, f[c].w, acc[c][k]);
            }
        }
    }

    // butterfly reduce over 64 lanes (each lane held a disjoint s-subset)
    #pragma unroll
    for (int c = 0; c < CPW; c++)
        #pragma unroll
        for (int k = 0; k < K; k++) {
            float v = acc[c][k];
            #pragma unroll
            for (int off = 32; off > 0; off >>= 1) v += __shfl_xor(v, off, 64);
            if (lane == 0)
                atomicAdd(&out[((size_t)b * C + c0 + c) * K + k], v);
        }
}

extern "C" void kernel_launch(void* const* d_in, const int* in_sizes, int n_in,
                              void* d_out, int out_size, void* d_ws, size_t ws_size,
                              hipStream_t stream) {
    const float* feats = (const float*)d_in[0];   // bb_feats [8,512,128,128]
    const float* aux   = (const float*)d_in[1];   // aux_out  [8,19,128,128]
    float* out   = (float*)d_out;                 // [8,512,19,1]
    float* stats = (float*)d_ws;                  // 152 * 2 floats

    hipMemsetAsync(d_out, 0, (size_t)out_size * sizeof(float), stream);
    softmax_stats_kernel<<<B * K, 1024, 0, stream>>>(aux, stats);
    gather_kernel<<<B * CG * NSC, 256, 0, stream>>>(feats, aux, stats, out);
}

// Round 3
// 471.846 us; speedup vs baseline: 2.8991x; 2.8991x over previous
//
#include <hip/hip_runtime.h>
#include <math.h>

#define B 8
#define C 512
#define K 19
#define HW 16384
#define L2E 1.44269504088896340736f

#define NW 4                     // waves per block
#define CPW 4                    // c-rows per wave -> acc[4][19] = 76 VGPRs
#define CPB (CPW * NW)           // 16 c-rows per block
#define CG (C / CPB)             // 32 c-groups
#define NSC 2                    // s-chunks -> grid = 8*32*2 = 512 = 2 blocks/CU
#define SCHUNK (HW / NSC)        // 8192 s per block
#define TS 256                   // s-tile staged in LDS
#define NT (SCHUNK / TS)         // 32 tiles per block

// Kernel 1: per-(b,k) softmax stats. stats[row*2] = -max*log2e, stats[row*2+1] = 1/Z
__global__ __launch_bounds__(1024)
void softmax_stats_kernel(const float* __restrict__ aux, float* __restrict__ stats) {
    int row = blockIdx.x;                          // 0 .. B*K-1
    const float4* x4 = (const float4*)(aux + (size_t)row * HW);
    int tid  = threadIdx.x;
    int lane = tid & 63;
    int wave = tid >> 6;
    __shared__ float red[16];

    float m = -INFINITY;
    #pragma unroll
    for (int i = 0; i < 4; i++) {
        float4 v = x4[tid + i * 1024];
        m = fmaxf(m, fmaxf(fmaxf(v.x, v.y), fmaxf(v.z, v.w)));
    }
    #pragma unroll
    for (int off = 32; off > 0; off >>= 1) m = fmaxf(m, __shfl_xor(m, off, 64));
    if (lane == 0) red[wave] = m;
    __syncthreads();
    #pragma unroll
    for (int w = 0; w < 16; w++) m = fmaxf(m, red[w]);
    __syncthreads();

    float ssum = 0.f;
    #pragma unroll
    for (int i = 0; i < 4; i++) {
        float4 v = x4[tid + i * 1024];
        ssum += exp2f((v.x - m) * L2E);
        ssum += exp2f((v.y - m) * L2E);
        ssum += exp2f((v.z - m) * L2E);
        ssum += exp2f((v.w - m) * L2E);
    }
    #pragma unroll
    for (int off = 32; off > 0; off >>= 1) ssum += __shfl_xor(ssum, off, 64);
    if (lane == 0) red[wave] = ssum;
    __syncthreads();
    if (tid == 0) {
        float Z = 0.f;
        #pragma unroll
        for (int w = 0; w < 16; w++) Z += red[w];
        stats[row * 2]     = -m * L2E;
        stats[row * 2 + 1] = 1.0f / Z;
    }
}

// Kernel 2: probs staged once per block per tile (double-buffered LDS), each
// wave FMAs 4 c-rows. amdgpu_waves_per_eu(2) pins the VGPR budget at 256 so
// acc[4][19]=76 + hoisted ds_read results never spill (R1/R2 failure mode).
__global__ __launch_bounds__(256)
__attribute__((amdgpu_waves_per_eu(2)))
void gather_kernel(const float* __restrict__ feats, const float* __restrict__ aux,
                   const float* __restrict__ stats, float* __restrict__ out) {
    __shared__ float plds[2][K][TS];          // 38,912 B
    __shared__ float ldspad[6272];            // +25,088 B -> 64,000 B total:
                                              // forces LDS-occupancy heuristic to 2 blocks/CU

    int bid  = blockIdx.x;                 // 0 .. 511
    int sc   = bid & (NSC - 1);
    int cg   = (bid >> 1) & (CG - 1);
    int b    = bid >> 6;                   // bid / (NSC*CG) = bid/64
    int tid  = threadIdx.x;
    int lane = tid & 63;
    int wave = tid >> 6;
    int c0   = cg * CPB + wave * CPW;

    const float* Abase = aux   + (size_t)b * K * HW + sc * SCHUNK;
    const float* Fbase = feats + ((size_t)b * C + c0) * HW + sc * SCHUNK;
    const float* S     = stats + (size_t)b * K * 2;

    // softmax stats -> SGPRs
    float negml[K], invz[K];
    #pragma unroll
    for (int k = 0; k < K; k++) {
        negml[k] = __int_as_float(__builtin_amdgcn_readfirstlane(__float_as_int(S[2 * k])));
        invz[k]  = __int_as_float(__builtin_amdgcn_readfirstlane(__float_as_int(S[2 * k + 1])));
    }
    // keep ldspad alive (branch never taken at runtime; not provably dead)
    if (__float_as_int(negml[0]) == 0x7f123456) ldspad[tid] = invz[0];

    float acc[CPW][K];
    #pragma unroll
    for (int c = 0; c < CPW; c++)
        #pragma unroll
        for (int k = 0; k < K; k++) acc[c][k] = 0.f;

    // prologue: stage tile 0 into buffer 0
    #pragma unroll
    for (int k = 0; k < K; k++) {
        float a = Abase[k * HW + tid];
        plds[0][k][tid] = exp2f(fmaf(a, L2E, negml[k])) * invz[k];
    }

    for (int t = 0; t < NT; t++) {
        int buf = t & 1;
        __syncthreads();   // staging of buf complete; prior FMA readers done

        // stage next tile into the other buffer (overlaps with FMA below)
        if (t + 1 < NT) {
            int s1 = (t + 1) * TS;
            #pragma unroll
            for (int k = 0; k < K; k++) {
                float a = Abase[k * HW + s1 + tid];
                plds[buf ^ 1][k][tid] = exp2f(fmaf(a, L2E, negml[k])) * invz[k];
            }
        }

        // compute on current buffer
        int s0 = t * TS;
        float4 f[CPW];
        #pragma unroll
        for (int c = 0; c < CPW; c++)
            f[c] = *(const float4*)(Fbase + c * HW + s0 + lane * 4);
        #pragma unroll
        for (int k = 0; k < K; k++) {
            float4 p4 = *(const float4*)(&plds[buf][k][lane * 4]);
            #pragma unroll
            for (int c = 0; c < CPW; c++) {
                acc[c][k] = fmaf(p4.x, f[c].x, acc[c][k]);
                acc[c][k] = fmaf(p4.y, f[c].y, acc[c][k]);
                acc[c][k] = fmaf(p4.z, f[c].z, acc[c][k]);
                acc[c][k] = fmaf(p4.w, f[c].w, acc[c][k]);
            }
        }
    }

    // butterfly reduce over 64 lanes, then one atomic per (c,k) per block
    #pragma unroll
    for (int c = 0; c < CPW; c++)
        #pragma unroll
        for (int k = 0; k < K; k++) {
            float v = acc[c][k];
            #pragma unroll
            for (int off = 32; off > 0; off >>= 1) v += __shfl_xor(v, off, 64);
            if (lane == 0)
                atomicAdd(&out[((size_t)b * C + c0 + c) * K + k], v);
        }
}

extern "C" void kernel_launch(void* const* d_in, const int* in_sizes, int n_in,
                              void* d_out, int out_size, void* d_ws, size_t ws_size,
                              hipStream_t stream) {
    const float* feats = (const float*)d_in[0];   // bb_feats [8,512,128,128]
    const float* aux   = (const float*)d_in[1];   // aux_out  [8,19,128,128]
    float* out   = (float*)d_out;                 // [8,512,19,1]
    float* stats = (float*)d_ws;                  // 152 * 2 floats

    hipMemsetAsync(d_out, 0, (size_t)out_size * sizeof(float), stream);
    softmax_stats_kernel<<<B * K, 1024, 0, stream>>>(aux, stats);
    gather_kernel<<<B * CG * NSC, 256, 0, stream>>>(feats, aux, stats, out);
}